// Round 2
// baseline (1288.673 us; speedup 1.0000x reference)
//
#include <hip/hip_runtime.h>
#include <hip/hip_cooperative_groups.h>
#include <math.h>

#define BS 1024
#define AA 3072
#define DD 2048
#define NTHR 256
#define MAXBLK 768        // 3 blocks/CU on 256 CUs (upper bound; clamped by occupancy)

namespace cg = cooperative_groups;

struct Params {
    const float* x;
    const float* W[8];
    const float* B[8];
    float* act[9];          // act[1..8] layer outputs (act[8]=out_y)
    float* out_ind;         // [BS*BS]
    float* out_lat;         // [BS*BS]
    float* out_rep;         // [DD] copy of yy
};

// Copy IN_DIM floats from global `in` into LDS xs. IN_DIM/4 is a multiple of NTHR.
template<int IN_DIM>
__device__ __forceinline__ void stage(const float* __restrict__ in, float* xs)
{
    const float4* __restrict__ inv = (const float4*)in;
    float4* xs4 = (float4*)xs;
#pragma unroll
    for (int i = 0; i < IN_DIM / 4 / NTHR; ++i)
        xs4[threadIdx.x + i * NTHR] = inv[threadIdx.x + i * NTHR];
}

// One wave per output row: out[r] = act(dot(W[r,:], xs) + b[r]).
// ACT: 0=none, 1=tanh, 2=tanhshrink. Grid-stride over rows.
template<int IN_DIM, int ACT>
__device__ __forceinline__ void layer_compute(
    const float* __restrict__ W, const float* __restrict__ b,
    const float* __restrict__ xs, float* __restrict__ out,
    float* __restrict__ out2, int out_dim, int wv, int lane, int totw)
{
    const float4* __restrict__ xs4 = (const float4*)xs;
    constexpr int N4 = IN_DIM / 4;
    for (int r = wv; r < out_dim; r += totw) {
        const float4* __restrict__ Wr = (const float4*)(W + (size_t)r * IN_DIM);
        float sum = 0.f;
#pragma unroll
        for (int it = 0; it < N4 / 64; ++it) {
            int i = lane + it * 64;        // coalesced 16B/lane
            float4 w4 = Wr[i];
            float4 x4 = xs4[i];
            sum += w4.x * x4.x + w4.y * x4.y + w4.z * x4.z + w4.w * x4.w;
        }
#pragma unroll
        for (int off = 32; off; off >>= 1) sum += __shfl_down(sum, off);
        if (lane == 0) {
            float v = sum + b[r];
            if (ACT == 1)      v = tanhf(v);
            else if (ACT == 2) v = v - tanhf(v);   // Tanhshrink
            out[r] = v;
            if (out2) out2[r] = v;
        }
    }
}

__global__ __launch_bounds__(NTHR, 3) void fused_ae(Params p)
{
    __shared__ float xs[AA];               // 12 KB
    cg::grid_group grid = cg::this_grid();

    const int nthr_tot = (int)(gridDim.x * NTHR);
    const int tid  = (int)(blockIdx.x * NTHR + threadIdx.x);
    const int wv   = tid >> 6;
    const int lane = (int)(threadIdx.x & 63);
    const int totw = nthr_tot >> 6;

    // ---- stage x; pdist3 reads it from LDS (independent, fire-and-forget) ----
    stage<AA>(p.x, xs);
    __syncthreads();
    for (int idx = tid; idx < BS * BS; idx += nthr_tot) {
        int i = idx >> 10, j = idx & 1023;
        float d0 = xs[3 * i + 0] - xs[3 * j + 0];
        float d1 = xs[3 * i + 1] - xs[3 * j + 1];
        float d2 = xs[3 * i + 2] - xs[3 * j + 2];
        p.out_ind[idx] = sqrtf(d0 * d0 + d1 * d1 + d2 * d2);
    }

    // ---- encoder ----
    layer_compute<AA, 1>(p.W[0], p.B[0], xs, p.act[1], nullptr, AA, wv, lane, totw);
    __threadfence(); grid.sync(); __threadfence();
    stage<AA>(p.act[1], xs); __syncthreads();
    layer_compute<AA, 1>(p.W[1], p.B[1], xs, p.act[2], nullptr, AA, wv, lane, totw);
    __threadfence(); grid.sync(); __threadfence();
    stage<AA>(p.act[2], xs); __syncthreads();
    layer_compute<AA, 0>(p.W[2], p.B[2], xs, p.act[3], nullptr, AA, wv, lane, totw);
    __threadfence(); grid.sync(); __threadfence();
    stage<AA>(p.act[3], xs); __syncthreads();
    layer_compute<AA, 2>(p.W[3], p.B[3], xs, p.act[4], p.out_rep, DD, wv, lane, totw);
    __threadfence(); grid.sync(); __threadfence();

    // ---- yy ready: stage it; pdist2 from LDS; then decoder ----
    stage<DD>(p.act[4], xs); __syncthreads();
    for (int idx = tid; idx < BS * BS; idx += nthr_tot) {
        int i = idx >> 10, j = idx & 1023;
        float d0 = xs[2 * i + 0] - xs[2 * j + 0];
        float d1 = xs[2 * i + 1] - xs[2 * j + 1];
        p.out_lat[idx] = sqrtf(d0 * d0 + d1 * d1);
    }
    layer_compute<DD, 1>(p.W[4], p.B[4], xs, p.act[5], nullptr, AA, wv, lane, totw);
    __threadfence(); grid.sync(); __threadfence();
    stage<AA>(p.act[5], xs); __syncthreads();
    layer_compute<AA, 1>(p.W[5], p.B[5], xs, p.act[6], nullptr, AA, wv, lane, totw);
    __threadfence(); grid.sync(); __threadfence();
    stage<AA>(p.act[6], xs); __syncthreads();
    layer_compute<AA, 0>(p.W[6], p.B[6], xs, p.act[7], nullptr, AA, wv, lane, totw);
    __threadfence(); grid.sync(); __threadfence();
    stage<AA>(p.act[7], xs); __syncthreads();
    layer_compute<AA, 1>(p.W[7], p.B[7], xs, p.act[8], nullptr, AA, wv, lane, totw);
}

// ---------------- fallback path (known-good round-0 kernels) ----------------

template<int IN_DIM, int ACT>
__global__ __launch_bounds__(256) void matvec_act(
    const float* __restrict__ W, const float* __restrict__ b,
    const float* __restrict__ x, float* __restrict__ y,
    float* __restrict__ y2, int out_dim)
{
    int row  = (int)((blockIdx.x * blockDim.x + threadIdx.x) >> 6);
    int lane = (int)(threadIdx.x & 63);
    if (row >= out_dim) return;

    const float4* __restrict__ Wr = (const float4*)(W + (size_t)row * IN_DIM);
    const float4* __restrict__ xv = (const float4*)x;

    constexpr int N4 = IN_DIM / 4;
    float sum = 0.f;
#pragma unroll
    for (int it = 0; it < N4 / 64; ++it) {
        int i = lane + it * 64;
        float4 w4 = Wr[i];
        float4 x4 = xv[i];
        sum += w4.x * x4.x + w4.y * x4.y + w4.z * x4.z + w4.w * x4.w;
    }
#pragma unroll
    for (int off = 32; off; off >>= 1) sum += __shfl_down(sum, off);
    if (lane == 0) {
        float v = sum + b[row];
        if (ACT == 1)      v = tanhf(v);
        else if (ACT == 2) v = v - tanhf(v);
        y[row] = v;
        if (y2) y2[row] = v;
    }
}

__global__ __launch_bounds__(256) void pdist3_kernel(
    const float* __restrict__ a, float* __restrict__ out)
{
    int idx = (int)(blockIdx.x * blockDim.x + threadIdx.x);
    int i = idx >> 10, j = idx & 1023;
    float d0 = a[3 * i + 0] - a[3 * j + 0];
    float d1 = a[3 * i + 1] - a[3 * j + 1];
    float d2 = a[3 * i + 2] - a[3 * j + 2];
    out[idx] = sqrtf(d0 * d0 + d1 * d1 + d2 * d2);
}

__global__ __launch_bounds__(256) void pdist2_kernel(
    const float* __restrict__ a, float* __restrict__ out)
{
    int idx = (int)(blockIdx.x * blockDim.x + threadIdx.x);
    int i = idx >> 10, j = idx & 1023;
    float d0 = a[2 * i + 0] - a[2 * j + 0];
    float d1 = a[2 * i + 1] - a[2 * j + 1];
    out[idx] = sqrtf(d0 * d0 + d1 * d1);
}

extern "C" void kernel_launch(void* const* d_in, const int* in_sizes, int n_in,
                              void* d_out, int out_size, void* d_ws, size_t ws_size,
                              hipStream_t stream)
{
    const float* x   = (const float*)d_in[0];
    const float* ew1 = (const float*)d_in[1];  const float* eb1 = (const float*)d_in[2];
    const float* ew2 = (const float*)d_in[3];  const float* eb2 = (const float*)d_in[4];
    const float* ew3 = (const float*)d_in[5];  const float* eb3 = (const float*)d_in[6];
    const float* ew4 = (const float*)d_in[7];  const float* eb4 = (const float*)d_in[8];
    const float* dw1 = (const float*)d_in[9];  const float* db1 = (const float*)d_in[10];
    const float* dw2 = (const float*)d_in[11]; const float* db2 = (const float*)d_in[12];
    const float* dw3 = (const float*)d_in[13]; const float* db3 = (const float*)d_in[14];
    const float* dw4 = (const float*)d_in[15]; const float* db4 = (const float*)d_in[16];

    float* out      = (float*)d_out;
    float* out_y    = out;                     // [3072]
    float* out_ind  = out + AA;                // [BS*BS]
    float* out_lat  = out_ind + BS * BS;       // [BS*BS]
    float* out_rep  = out_lat + BS * BS;       // [2048]

    float* ws = (float*)d_ws;
    float* h1 = ws;            // [3072]
    float* h2 = h1 + AA;       // [3072]
    float* h3 = h2 + AA;       // [3072]
    float* yy = h3 + AA;       // [2048]
    float* g1 = yy + DD;       // [3072]
    float* g2 = g1 + AA;       // [3072]
    float* g3 = g2 + AA;       // [3072]

    // ---- decide cooperative grid size once (capture-safe host queries) ----
    static int s_nblk = 0;     // 0 = uninitialized, -1 = coop disabled
    if (s_nblk == 0) {
        int occ = 0;
        hipError_t e = hipOccupancyMaxActiveBlocksPerMultiprocessor(&occ, fused_ae, NTHR, 0);
        if (e == hipSuccess && occ > 0) {
            int cus = 256, dev = 0;
            hipGetDevice(&dev);
            hipDeviceProp_t prop;
            if (hipGetDeviceProperties(&prop, dev) == hipSuccess && prop.multiProcessorCount > 0)
                cus = prop.multiProcessorCount;
            long total = (long)occ * (long)cus;
            s_nblk = (int)(total < MAXBLK ? total : MAXBLK);
            if (s_nblk <= 0) s_nblk = -1;
        } else {
            s_nblk = -1;
        }
    }

    bool done = false;
    if (s_nblk > 0) {
        Params p;
        p.x = x;
        p.W[0] = ew1; p.B[0] = eb1; p.W[1] = ew2; p.B[1] = eb2;
        p.W[2] = ew3; p.B[2] = eb3; p.W[3] = ew4; p.B[3] = eb4;
        p.W[4] = dw1; p.B[4] = db1; p.W[5] = dw2; p.B[5] = db2;
        p.W[6] = dw3; p.B[6] = db3; p.W[7] = dw4; p.B[7] = db4;
        p.act[0] = nullptr;
        p.act[1] = h1; p.act[2] = h2; p.act[3] = h3; p.act[4] = yy;
        p.act[5] = g1; p.act[6] = g2; p.act[7] = g3; p.act[8] = out_y;
        p.out_ind = out_ind; p.out_lat = out_lat; p.out_rep = out_rep;

        void* args[] = { (void*)&p };
        hipError_t e = hipLaunchCooperativeKernel((void*)fused_ae, dim3(s_nblk), dim3(NTHR),
                                                  args, 0, stream);
        if (e == hipSuccess) done = true;
        else s_nblk = -1;                 // don't retry; use fallback from now on
    }

    if (!done) {
        dim3 blk(256);
        pdist3_kernel<<<BS * BS / 256, blk, 0, stream>>>(x, out_ind);
        matvec_act<AA, 1><<<AA / 4, blk, 0, stream>>>(ew1, eb1, x,  h1, nullptr, AA);
        matvec_act<AA, 1><<<AA / 4, blk, 0, stream>>>(ew2, eb2, h1, h2, nullptr, AA);
        matvec_act<AA, 0><<<AA / 4, blk, 0, stream>>>(ew3, eb3, h2, h3, nullptr, AA);
        matvec_act<DD, 2><<<DD / 4, blk, 0, stream>>>(ew4, eb4, h3, yy, out_rep, DD);
        pdist2_kernel<<<BS * BS / 256, blk, 0, stream>>>(yy, out_lat);
        matvec_act<DD, 1><<<AA / 4, blk, 0, stream>>>(dw1, db1, yy, g1, nullptr, AA);
        matvec_act<AA, 1><<<AA / 4, blk, 0, stream>>>(dw2, db2, g1, g2, nullptr, AA);
        matvec_act<AA, 0><<<AA / 4, blk, 0, stream>>>(dw3, db3, g2, g3, nullptr, AA);
        matvec_act<AA, 1><<<AA / 4, blk, 0, stream>>>(dw4, db4, g3, out_y, nullptr, AA);
    }
}

// Round 3
// 290.672 us; speedup vs baseline: 4.4334x; 4.4334x over previous
//
#include <hip/hip_runtime.h>
#include <math.h>

#define BS 1024
#define AA 3072
#define DD 2048

// One block (256 threads = 4 waves) per output row.
// Grid = out_dim blocks -> 3072 (or 2048) blocks, 8 blocks/CU co-resident
// (__launch_bounds__(256,8) caps VGPR at 64 -> 32 waves/CU, full occupancy).
// Lane t covers W_row float4s {t, t+256, t+512}: coalesced 1KB/instr segments.
// x is read from global; it is 12KB and L2-resident after first touch per XCD,
// so it adds no HBM traffic. ACT: 0=none, 1=tanh, 2=tanhshrink.
template<int IN_DIM, int ACT>
__global__ __launch_bounds__(256, 8) void matvec_row(
    const float* __restrict__ W, const float* __restrict__ b,
    const float* __restrict__ x, float* __restrict__ y,
    float* __restrict__ y2)
{
    const int row = (int)blockIdx.x;
    const int t   = (int)threadIdx.x;

    const float4* __restrict__ Wr = (const float4*)(W + (size_t)row * IN_DIM);
    const float4* __restrict__ xv = (const float4*)x;

    constexpr int N4 = IN_DIM / 4;         // 768 (AA) or 512 (DD)
    float sum = 0.f;
#pragma unroll
    for (int it = 0; it < N4 / 256; ++it) {
        int i = t + it * 256;
        float4 w4 = Wr[i];
        float4 x4 = xv[i];
        sum += w4.x * x4.x + w4.y * x4.y + w4.z * x4.z + w4.w * x4.w;
    }

    // intra-wave reduce
#pragma unroll
    for (int off = 32; off; off >>= 1) sum += __shfl_down(sum, off);

    // cross-wave reduce (4 waves)
    __shared__ float part[4];
    if ((t & 63) == 0) part[t >> 6] = sum;
    __syncthreads();
    if (t == 0) {
        float v = part[0] + part[1] + part[2] + part[3] + b[row];
        if (ACT == 1)      v = tanhf(v);
        else if (ACT == 2) v = v - tanhf(v);   // Tanhshrink
        y[row] = v;
        if (y2) y2[row] = v;
    }
}

// Pairwise Euclidean distances, 3-dim points, a:[1024,3] -> out:[1024*1024]
__global__ __launch_bounds__(256) void pdist3_kernel(
    const float* __restrict__ a, float* __restrict__ out)
{
    int idx = (int)(blockIdx.x * blockDim.x + threadIdx.x);
    int i = idx >> 10, j = idx & 1023;
    float d0 = a[3 * i + 0] - a[3 * j + 0];
    float d1 = a[3 * i + 1] - a[3 * j + 1];
    float d2 = a[3 * i + 2] - a[3 * j + 2];
    out[idx] = sqrtf(d0 * d0 + d1 * d1 + d2 * d2);
}

// Pairwise Euclidean distances, 2-dim points, a:[1024,2] -> out:[1024*1024]
__global__ __launch_bounds__(256) void pdist2_kernel(
    const float* __restrict__ a, float* __restrict__ out)
{
    int idx = (int)(blockIdx.x * blockDim.x + threadIdx.x);
    int i = idx >> 10, j = idx & 1023;
    float d0 = a[2 * i + 0] - a[2 * j + 0];
    float d1 = a[2 * i + 1] - a[2 * j + 1];
    out[idx] = sqrtf(d0 * d0 + d1 * d1);
}

extern "C" void kernel_launch(void* const* d_in, const int* in_sizes, int n_in,
                              void* d_out, int out_size, void* d_ws, size_t ws_size,
                              hipStream_t stream)
{
    const float* x   = (const float*)d_in[0];
    const float* ew1 = (const float*)d_in[1];  const float* eb1 = (const float*)d_in[2];
    const float* ew2 = (const float*)d_in[3];  const float* eb2 = (const float*)d_in[4];
    const float* ew3 = (const float*)d_in[5];  const float* eb3 = (const float*)d_in[6];
    const float* ew4 = (const float*)d_in[7];  const float* eb4 = (const float*)d_in[8];
    const float* dw1 = (const float*)d_in[9];  const float* db1 = (const float*)d_in[10];
    const float* dw2 = (const float*)d_in[11]; const float* db2 = (const float*)d_in[12];
    const float* dw3 = (const float*)d_in[13]; const float* db3 = (const float*)d_in[14];
    const float* dw4 = (const float*)d_in[15]; const float* db4 = (const float*)d_in[16];

    float* out      = (float*)d_out;
    float* out_y    = out;                     // output        [3072]
    float* out_ind  = out + AA;                // in_diff_sum   [1024*1024]
    float* out_lat  = out_ind + BS * BS;       // lat_diff_sum  [1024*1024]
    float* out_rep  = out_lat + BS * BS;       // lat_repr      [2048]

    float* ws = (float*)d_ws;
    float* h1 = ws;            // [3072]
    float* h2 = h1 + AA;       // [3072]
    float* h3 = h2 + AA;       // [3072]
    float* yy = h3 + AA;       // [2048]
    float* g1 = yy + DD;       // [3072]
    float* g2 = g1 + AA;       // [3072]
    float* g3 = g2 + AA;       // [3072]

    dim3 blk(256);

    // in_diff depends only on x — launch first
    pdist3_kernel<<<BS * BS / 256, blk, 0, stream>>>(x, out_ind);

    // encoder
    matvec_row<AA, 1><<<AA, blk, 0, stream>>>(ew1, eb1, x,  h1, nullptr);
    matvec_row<AA, 1><<<AA, blk, 0, stream>>>(ew2, eb2, h1, h2, nullptr);
    matvec_row<AA, 0><<<AA, blk, 0, stream>>>(ew3, eb3, h2, h3, nullptr);
    matvec_row<AA, 2><<<DD, blk, 0, stream>>>(ew4, eb4, h3, yy, out_rep);

    // lat_diff on y
    pdist2_kernel<<<BS * BS / 256, blk, 0, stream>>>(yy, out_lat);

    // decoder
    matvec_row<DD, 1><<<AA, blk, 0, stream>>>(dw1, db1, yy, g1, nullptr);
    matvec_row<AA, 1><<<AA, blk, 0, stream>>>(dw2, db2, g1, g2, nullptr);
    matvec_row<AA, 0><<<AA, blk, 0, stream>>>(dw3, db3, g2, g3, nullptr);
    matvec_row<AA, 1><<<AA, blk, 0, stream>>>(dw4, db4, g3, out_y, nullptr);
}

// Round 4
// 286.223 us; speedup vs baseline: 4.5023x; 1.0155x over previous
//
#include <hip/hip_runtime.h>
#include <math.h>

#define BS 1024
#define AA 3072
#define DD 2048
#define PDBLK (BS * BS / 256)   // 4096 blocks of pdist work

// One block (256 threads = 4 waves) per output row, rows = first NROW blocks.
// Blocks [NROW, NROW+PDBLK) compute pdist on the SAME input vector x (valid:
// pdist reads only the dispatch's input, so no intra-dispatch dependency).
// Trailing pdist blocks backfill the matvec drain tail.
// ACT: 0=none, 1=tanh, 2=tanhshrink. PD: 0=none, 2/3 = pdist dims.
template<int IN_DIM, int ACT, int PD, int NROW>
__global__ __launch_bounds__(256, 8) void matvec_pd(
    const float* __restrict__ W, const float* __restrict__ b,
    const float* __restrict__ x, float* __restrict__ y,
    float* __restrict__ y2, float* __restrict__ pd_out)
{
    const int t = (int)threadIdx.x;

    if ((int)blockIdx.x >= NROW) {
        if (PD != 0) {
            int idx = (((int)blockIdx.x - NROW) << 8) | t;
            int i = idx >> 10, j = idx & 1023;
            if (PD == 3) {
                float d0 = x[3 * i + 0] - x[3 * j + 0];
                float d1 = x[3 * i + 1] - x[3 * j + 1];
                float d2 = x[3 * i + 2] - x[3 * j + 2];
                pd_out[idx] = sqrtf(d0 * d0 + d1 * d1 + d2 * d2);
            } else {
                float d0 = x[2 * i + 0] - x[2 * j + 0];
                float d1 = x[2 * i + 1] - x[2 * j + 1];
                pd_out[idx] = sqrtf(d0 * d0 + d1 * d1);
            }
        }
        return;
    }

    const int row = (int)blockIdx.x;
    const float4* __restrict__ Wr = (const float4*)(W + (size_t)row * IN_DIM);
    const float4* __restrict__ xv = (const float4*)x;

    constexpr int N4 = IN_DIM / 4;         // 768 (AA) or 512 (DD)
    float sum = 0.f;
#pragma unroll
    for (int it = 0; it < N4 / 256; ++it) {
        int i = t + it * 256;              // coalesced: 1KB/wave/instr
        float4 w4 = Wr[i];
        float4 x4 = xv[i];
        sum += w4.x * x4.x + w4.y * x4.y + w4.z * x4.z + w4.w * x4.w;
    }

    // intra-wave reduce
#pragma unroll
    for (int off = 32; off; off >>= 1) sum += __shfl_down(sum, off);

    // cross-wave reduce (4 waves)
    __shared__ float part[4];
    if ((t & 63) == 0) part[t >> 6] = sum;
    __syncthreads();
    if (t == 0) {
        float v = part[0] + part[1] + part[2] + part[3] + b[row];
        if (ACT == 1)      v = tanhf(v);
        else if (ACT == 2) v = v - tanhf(v);   // Tanhshrink
        y[row] = v;
        if (y2) y2[row] = v;
    }
}

extern "C" void kernel_launch(void* const* d_in, const int* in_sizes, int n_in,
                              void* d_out, int out_size, void* d_ws, size_t ws_size,
                              hipStream_t stream)
{
    const float* x   = (const float*)d_in[0];
    const float* ew1 = (const float*)d_in[1];  const float* eb1 = (const float*)d_in[2];
    const float* ew2 = (const float*)d_in[3];  const float* eb2 = (const float*)d_in[4];
    const float* ew3 = (const float*)d_in[5];  const float* eb3 = (const float*)d_in[6];
    const float* ew4 = (const float*)d_in[7];  const float* eb4 = (const float*)d_in[8];
    const float* dw1 = (const float*)d_in[9];  const float* db1 = (const float*)d_in[10];
    const float* dw2 = (const float*)d_in[11]; const float* db2 = (const float*)d_in[12];
    const float* dw3 = (const float*)d_in[13]; const float* db3 = (const float*)d_in[14];
    const float* dw4 = (const float*)d_in[15]; const float* db4 = (const float*)d_in[16];

    float* out      = (float*)d_out;
    float* out_y    = out;                     // output        [3072]
    float* out_ind  = out + AA;                // in_diff_sum   [1024*1024]
    float* out_lat  = out_ind + BS * BS;       // lat_diff_sum  [1024*1024]
    float* out_rep  = out_lat + BS * BS;       // lat_repr      [2048]

    float* ws = (float*)d_ws;
    float* h1 = ws;            // [3072]
    float* h2 = h1 + AA;       // [3072]
    float* h3 = h2 + AA;       // [3072]
    float* yy = h3 + AA;       // [2048]
    float* g1 = yy + DD;       // [3072]
    float* g2 = g1 + AA;       // [3072]
    float* g3 = g2 + AA;       // [3072]

    dim3 blk(256);

    // encoder (pdist3 on x rides along with layer 1)
    matvec_pd<AA, 1, 3, AA><<<AA + PDBLK, blk, 0, stream>>>(ew1, eb1, x,  h1, nullptr, out_ind);
    matvec_pd<AA, 1, 0, AA><<<AA,         blk, 0, stream>>>(ew2, eb2, h1, h2, nullptr, nullptr);
    matvec_pd<AA, 0, 0, AA><<<AA,         blk, 0, stream>>>(ew3, eb3, h2, h3, nullptr, nullptr);
    matvec_pd<AA, 2, 0, DD><<<DD,         blk, 0, stream>>>(ew4, eb4, h3, yy, out_rep, nullptr);

    // decoder (pdist2 on yy rides along with layer 1)
    matvec_pd<DD, 1, 2, AA><<<AA + PDBLK, blk, 0, stream>>>(dw1, db1, yy, g1, nullptr, out_lat);
    matvec_pd<AA, 1, 0, AA><<<AA,         blk, 0, stream>>>(dw2, db2, g1, g2, nullptr, nullptr);
    matvec_pd<AA, 0, 0, AA><<<AA,         blk, 0, stream>>>(dw3, db3, g2, g3, nullptr, nullptr);
    matvec_pd<AA, 1, 0, AA><<<AA,         blk, 0, stream>>>(dw4, db4, g3, out_y, nullptr, nullptr);
}